// Round 17
// baseline (213.541 us; speedup 1.0000x reference)
//
#include <hip/hip_runtime.h>
#include <math.h>

#define NF 128
#define HD 8
#define NPG 2000          // nodes per graph
#define EPB 8000          // edges per sort chunk (4 chunks per graph)
#define FNPB 128          // nodes per feat block (1024 thr)
#define SLOPE 0.01f

__device__ __forceinline__ float lrelu(float v) {
    return v > 0.0f ? v : SLOPE * v;
}
// bf16 helpers: RNE pack, cheap unpack
__device__ __forceinline__ unsigned short f2bf(float f) {
    unsigned int u = __float_as_uint(f);
    return (unsigned short)((u + 0x7FFFu + ((u >> 16) & 1u)) >> 16);
}
__device__ __forceinline__ float bfl(unsigned int p) {
    return __uint_as_float(p << 16);
}
__device__ __forceinline__ float bfh(unsigned int p) {
    return __uint_as_float(p & 0xFFFF0000u);
}

// ---------------------------------------------------------------------------
// K1: fused [sort 0..255: single global pass (packed edges staged in LDS)] +
//          [feat 256..1255: 128 nodes, thread=(node,col), bf16 t1 store].
// (byte-identical to R16)
// ---------------------------------------------------------------------------
__global__ __launch_bounds__(1024) void k_featsort(
    const float* __restrict__ x, const float* __restrict__ W1a,
    const int* __restrict__ ei, unsigned short* __restrict__ t1b,
    unsigned short* __restrict__ gcolb, int* __restrict__ rpc,
    int N, int E, int NC)
{
    __shared__ union {
        struct { float tile[FNPB * 132]; float wl[NF * HD]; } f;  // 71.7 KB
        struct { int cnt[NPG]; unsigned int pck[EPB]; int srt[EPB];
                 int wtot[16]; int wpre[16]; } s;                 // 72.3 KB
    } sm;

    const int tid = threadIdx.x;

    if ((int)blockIdx.x < NC) {
        const int b = blockIdx.x;
        const int g = b >> 2;
        const int lane = tid & 63;
        const int wv = tid >> 6;
        const int nodeBase = g * NPG;
        const int e0 = b * EPB;

        for (int i = tid; i < NPG; i += 1024) sm.s.cnt[i] = 0;
        __syncthreads();

        for (int e = e0 + tid; e < e0 + EPB; e += 1024) {
            int src = ei[e] - nodeBase;               // < 2048
            int dl = ei[E + e] - nodeBase;            // < 2048
            sm.s.pck[e - e0] = ((unsigned int)dl << 11) | (unsigned int)src;
            atomicAdd(&sm.s.cnt[dl], 1);              // native ds_add_u32
        }
        __syncthreads();

        int c0 = 0, c1 = 0;
        if (tid < 1000) { c0 = sm.s.cnt[2 * tid]; c1 = sm.s.cnt[2 * tid + 1]; }
        int s = c0 + c1;
        int isc = s;
#pragma unroll
        for (int d = 1; d < 64; d <<= 1) {
            int o = __shfl_up(isc, d);
            if (lane >= d) isc += o;
        }
        if (lane == 63) sm.s.wtot[wv] = isc;
        __syncthreads();
        if (wv == 0) {
            int v = (lane < 16) ? sm.s.wtot[lane] : 0;
            int iv = v;
#pragma unroll
            for (int d = 1; d < 16; d <<= 1) {
                int o = __shfl_up(iv, d);
                if (lane >= d) iv += o;
            }
            if (lane < 16) sm.s.wpre[lane] = iv - v;
        }
        __syncthreads();
        int excl = isc - s + sm.s.wpre[wv];

        int* rpb = rpc + (size_t)b * (NPG + 1);
        if (tid < 1000) {
            sm.s.cnt[2 * tid]     = excl;
            sm.s.cnt[2 * tid + 1] = excl + c0;
            rpb[2 * tid]     = excl;
            rpb[2 * tid + 1] = excl + c0;
        }
        if (tid == 0) rpb[NPG] = EPB;
        __syncthreads();

        for (int i = tid; i < EPB; i += 1024) {
            unsigned int p = sm.s.pck[i];
            int dl = (int)(p >> 11);
            int src = (int)(p & 2047u);
            int pos = atomicAdd(&sm.s.cnt[dl], 1);    // ds_add_rtn_u32
            sm.s.srt[pos] = src;
        }
        __syncthreads();

        unsigned int* dst = (unsigned int*)(gcolb + (size_t)b * EPB);
        for (int i = tid; i < EPB / 2; i += 1024) {
            unsigned int lo = (unsigned int)sm.s.srt[2 * i] & 0xFFFFu;
            unsigned int hi = (unsigned int)sm.s.srt[2 * i + 1] << 16;
            dst[i] = lo | hi;
        }
    } else {
        const size_t base = (size_t)(blockIdx.x - NC) * FNPB;

        if (tid < 256) ((float4*)sm.f.wl)[tid] = ((const float4*)W1a)[tid];

        const float4* xg = (const float4*)(x + base * NF);
#pragma unroll
        for (int i = 0; i < 4; ++i) {
            int idx = tid + i * 1024;
            float4 v = xg[idx];
            int n = idx >> 5;
            int k4 = idx & 31;
            *(float4*)(sm.f.tile + n * 132 + k4 * 4) = v;
        }
        __syncthreads();

        const int n = tid >> 3;
        const int col = tid & 7;
        float acc = 0.0f;
        const float* row = sm.f.tile + n * 132;
#pragma unroll
        for (int k4 = 0; k4 < 32; ++k4) {
            float4 r = *(const float4*)(row + k4 * 4);
            int kb = k4 * 4 * HD + col;
            acc += r.x * sm.f.wl[kb];
            acc += r.y * sm.f.wl[kb + HD];
            acc += r.z * sm.f.wl[kb + 2 * HD];
            acc += r.w * sm.f.wl[kb + 3 * HD];
        }
        t1b[(base + n) * HD + col] = f2bf(acc);
    }
}

// ---------------------------------------------------------------------------
// Batched gather: 8 independent clamped col loads, then 8 predicated LDS
// gathers; rare tail for degree > 8.
// ---------------------------------------------------------------------------
#define GATHER_CHUNK(P)                                                       \
    {                                                                         \
        int b0 = rs[P], cnt = re[P] - b0;                                     \
        int sl[8];                                                            \
        _Pragma("unroll")                                                     \
        for (int j = 0; j < 8; ++j) {                                         \
            int idx = (j < cnt) ? (b0 + j) : 0;                               \
            sl[j] = colp[P][idx];                                             \
        }                                                                     \
        _Pragma("unroll")                                                     \
        for (int j = 0; j < 8; ++j) {                                         \
            float w = (j < cnt) ? 1.0f : 0.0f;                                \
            uint4 v = tbl[sl[j]];                                             \
            a0 += w * bfl(v.x); a1 += w * bfh(v.x);                           \
            a2 += w * bfl(v.y); a3 += w * bfh(v.y);                           \
            a4 += w * bfl(v.z); a5 += w * bfh(v.z);                           \
            a6 += w * bfl(v.w); a7 += w * bfh(v.w);                           \
        }                                                                     \
        for (int e2 = b0 + 8; e2 < b0 + cnt; ++e2) {                          \
            uint4 v = tbl[colp[P][e2]];                                       \
            a0 += bfl(v.x); a1 += bfh(v.x);                                   \
            a2 += bfl(v.y); a3 += bfh(v.y);                                   \
            a4 += bfl(v.z); a5 += bfh(v.z);                                   \
            a6 += bfl(v.w); a7 += bfh(v.w);                                   \
        }                                                                     \
    }

// ---------------------------------------------------------------------------
// K2: FUSED layers + readout. One block (1024 thr) per graph; 2 nodes/thread.
// Phase 1: stage t1 slice (32 KB) -> l1 gather+MLP1 (u in registers).
// Phase 2: overwrite LDS table with packed u (no global u round-trip).
// Phase 3: l2 gather+MLP2+FC1+FC2 partials -> block reduce -> log_softmax.
// Deletes 2 launches, 2 gaps, 1 staging pass, 8 MB of u traffic vs R16.
// Plain launch_bounds(1024): VGPR<=128 (the R11 trap was the <=64 cap).
// ---------------------------------------------------------------------------
__global__ __launch_bounds__(1024) void k_layers(
    const unsigned short* __restrict__ t1b, const int* __restrict__ rpc,
    const unsigned short* __restrict__ gcolb,
    const float* __restrict__ b1a, const float* __restrict__ W1b,
    const float* __restrict__ b1b, const float* __restrict__ W2a,
    const float* __restrict__ b2a, const float* __restrict__ W2b,
    const float* __restrict__ b2b, const float* __restrict__ Wf1,
    const float* __restrict__ bf1, const float* __restrict__ Wf2,
    const float* __restrict__ bf2, float* __restrict__ out)
{
    __shared__ uint4 tbl[NPG];        // 32 KB (t1 in phase 1, u in phase 3)
    __shared__ float w1[144];         // b1a[8] W1b[64] b1b[8] W2a[64]
    __shared__ float w2[89];          // b2a[8] W2b[64] b2b[8] Wf1[8] bf1[1]
    __shared__ float red[32];

    const int g = blockIdx.x;
    const int tid = threadIdx.x;
    const int lane = tid & 63;
    const int wv = tid >> 6;

    if (tid < 144) {
        float v;
        if (tid < 8)       v = b1a[tid];
        else if (tid < 72) v = W1b[tid - 8];
        else if (tid < 80) v = b1b[tid - 72];
        else               v = W2a[tid - 80];
        w1[tid] = v;
    }
    if (tid >= 256 && tid < 345) {
        int i = tid - 256;
        float v;
        if (i < 8)       v = b2a[i];
        else if (i < 72) v = W2b[i - 8];
        else if (i < 80) v = b2b[i - 72];
        else if (i < 88) v = Wf1[i - 80];
        else             v = bf1[0];
        w2[i] = v;
    }

    // stage t1 slice (2000 uint4), coalesced
    const uint4* src4 = (const uint4*)(t1b + (size_t)g * NPG * HD);
    if (tid < NPG) tbl[tid] = src4[tid];
    {
        int idx = tid + 1024;
        if (idx < NPG) tbl[idx] = src4[idx];
    }
    __syncthreads();

    // CSR chunk pointers for this graph
    const int* rpb4[4];
    const unsigned short* colp[4];
#pragma unroll
    for (int p = 0; p < 4; ++p) {
        rpb4[p] = rpc + (size_t)((g << 2) + p) * (NPG + 1);
        colp[p] = gcolb + (size_t)((g << 2) + p) * EPB;
    }

    // ---- phase 1: l1 for 2 nodes/thread, u kept in registers ----
    uint4 upk[2];
#pragma unroll
    for (int s = 0; s < 2; ++s) {
        int nl = tid + s * 1024;
        if (nl < NPG) {
            int rs[4], re[4];
#pragma unroll
            for (int p = 0; p < 4; ++p) { rs[p] = rpb4[p][nl]; re[p] = rpb4[p][nl + 1]; }
            float a0 = 0, a1 = 0, a2 = 0, a3 = 0, a4 = 0, a5 = 0, a6 = 0, a7 = 0;
            GATHER_CHUNK(0) GATHER_CHUNK(1) GATHER_CHUNK(2) GATHER_CHUNK(3)

            uint4 sv = tbl[nl];
            float z[HD];
            z[0] = lrelu(bfl(sv.x) + a0 + w1[0]); z[1] = lrelu(bfh(sv.x) + a1 + w1[1]);
            z[2] = lrelu(bfl(sv.y) + a2 + w1[2]); z[3] = lrelu(bfh(sv.y) + a3 + w1[3]);
            z[4] = lrelu(bfl(sv.z) + a4 + w1[4]); z[5] = lrelu(bfh(sv.z) + a5 + w1[5]);
            z[6] = lrelu(bfl(sv.w) + a6 + w1[6]); z[7] = lrelu(bfh(sv.w) + a7 + w1[7]);

            float h[HD];
#pragma unroll
            for (int j = 0; j < HD; ++j) {
                float acc = w1[72 + j];
#pragma unroll
                for (int c = 0; c < HD; ++c) acc += z[c] * w1[8 + c * HD + j];
                h[j] = lrelu(acc);
            }
            float uu[HD];
#pragma unroll
            for (int j = 0; j < HD; ++j) {
                float acc = 0.0f;
#pragma unroll
                for (int c = 0; c < HD; ++c) acc += h[c] * w1[80 + c * HD + j];
                uu[j] = acc;
            }
            upk[s].x = (unsigned int)f2bf(uu[0]) | ((unsigned int)f2bf(uu[1]) << 16);
            upk[s].y = (unsigned int)f2bf(uu[2]) | ((unsigned int)f2bf(uu[3]) << 16);
            upk[s].z = (unsigned int)f2bf(uu[4]) | ((unsigned int)f2bf(uu[5]) << 16);
            upk[s].w = (unsigned int)f2bf(uu[6]) | ((unsigned int)f2bf(uu[7]) << 16);
        }
    }
    __syncthreads();   // all l1 reads of tbl complete

    // ---- phase 2: overwrite table with u ----
#pragma unroll
    for (int s = 0; s < 2; ++s) {
        int nl = tid + s * 1024;
        if (nl < NPG) tbl[nl] = upk[s];
    }
    __syncthreads();

    // ---- phase 3: l2 + MLP2 + FC1 + FC2 partials ----
    float acc0 = 0.0f, acc1 = 0.0f;
#pragma unroll
    for (int s = 0; s < 2; ++s) {
        int nl = tid + s * 1024;
        if (nl < NPG) {
            int rs[4], re[4];
#pragma unroll
            for (int p = 0; p < 4; ++p) { rs[p] = rpb4[p][nl]; re[p] = rpb4[p][nl + 1]; }
            float a0 = 0, a1 = 0, a2 = 0, a3 = 0, a4 = 0, a5 = 0, a6 = 0, a7 = 0;
            GATHER_CHUNK(0) GATHER_CHUNK(1) GATHER_CHUNK(2) GATHER_CHUNK(3)

            uint4 sv = tbl[nl];
            float z[HD];
            z[0] = lrelu(bfl(sv.x) + a0 + w2[0]); z[1] = lrelu(bfh(sv.x) + a1 + w2[1]);
            z[2] = lrelu(bfl(sv.y) + a2 + w2[2]); z[3] = lrelu(bfh(sv.y) + a3 + w2[3]);
            z[4] = lrelu(bfl(sv.z) + a4 + w2[4]); z[5] = lrelu(bfh(sv.z) + a5 + w2[5]);
            z[6] = lrelu(bfl(sv.w) + a6 + w2[6]); z[7] = lrelu(bfh(sv.w) + a7 + w2[7]);

            float sv2 = w2[88];
#pragma unroll
            for (int j = 0; j < HD; ++j) {
                float acc = w2[72 + j];
#pragma unroll
                for (int c = 0; c < HD; ++c) acc += z[c] * w2[8 + c * HD + j];
                sv2 += lrelu(acc) * w2[80 + j];
            }
            float pf = lrelu(sv2);
            float2 wf = *(const float2*)(Wf2 + (size_t)nl * 2);
            acc0 += pf * wf.x;
            acc1 += pf * wf.y;
        }
    }

    // ---- block reduce (16 waves) + log_softmax ----
#pragma unroll
    for (int off = 32; off > 0; off >>= 1) {
        acc0 += __shfl_down(acc0, off);
        acc1 += __shfl_down(acc1, off);
    }
    if (lane == 0) { red[wv * 2] = acc0; red[wv * 2 + 1] = acc1; }
    __syncthreads();
    if (tid == 0) {
        float y0 = bf2[0], y1 = bf2[1];
#pragma unroll
        for (int w = 0; w < 16; ++w) { y0 += red[w * 2]; y1 += red[w * 2 + 1]; }
        float m = fmaxf(y0, y1);
        float lse = m + logf(expf(y0 - m) + expf(y1 - m));
        out[g * 2 + 0] = y0 - lse;
        out[g * 2 + 1] = y1 - lse;
    }
}

// ---------------------------------------------------------------------------
extern "C" void kernel_launch(void* const* d_in, const int* in_sizes, int n_in,
                              void* d_out, int out_size, void* d_ws, size_t ws_size,
                              hipStream_t stream) {
    const float* x   = (const float*)d_in[0];
    const int*   ei  = (const int*)  d_in[1];
    const float* W1a = (const float*)d_in[3];
    const float* b1a = (const float*)d_in[4];
    const float* W1b = (const float*)d_in[5];
    const float* b1b = (const float*)d_in[6];
    const float* W2a = (const float*)d_in[7];
    const float* b2a = (const float*)d_in[8];
    const float* W2b = (const float*)d_in[9];
    const float* b2b = (const float*)d_in[10];
    const float* Wf1 = (const float*)d_in[11];
    const float* bf1 = (const float*)d_in[12];
    const float* Wf2 = (const float*)d_in[13];
    const float* bf2 = (const float*)d_in[14];

    int N   = in_sizes[0] / NF;        // 128000
    int E   = in_sizes[1] / 2;         // 2048000
    int Bn  = N / NPG;                 // 64 graphs
    int NC  = Bn * 4;                  // 256 chunks

    // workspace carve-up (16B-aligned sections)
    unsigned short* t1b   = (unsigned short*)d_ws;              // N*8 bf16  2.0 MB
    unsigned short* gcolb = t1b + (size_t)N * HD;               // E ushort  4.1 MB
    int*            rpc   = (int*)(gcolb + (size_t)E);          // NC*(NPG+1) 2.0 MB

    k_featsort<<<NC + N / FNPB, 1024, 0, stream>>>(x, W1a, ei, t1b, gcolb, rpc,
                                                   N, E, NC);
    k_layers  <<<Bn, 1024, 0, stream>>>(t1b, rpc, gcolb, b1a, W1b, b1b, W2a,
                                        b2a, W2b, b2b, Wf1, bf1, Wf2, bf2,
                                        (float*)d_out);
}